// Round 10
// baseline (129.014 us; speedup 1.0000x reference)
//
#include <hip/hip_runtime.h>
#include <math.h>

// N_NODES=100000, N_MOTIFS=1000000, R_DIM=1, D_DIM=64, N_GRAPHS=128.
// fp8 row = 64 B (16 u32 words).
//
// R10: stream/gather separation v2 (R4 retry, now with fp8 tables).
//  Pass A (gather): bellA[m] = q.(ku*kv). Working set = 12.8MB fp8 tables
//    + 12MB idx, NO stream pollution -> cache-serviceable.
//  Pass B (stream): T 256MB nt + 6.4MB fp8 q + bellA -> exp + atomic.
// Each pass runs near its own roofline instead of the stream forcing the
// gathers to HBM (R7/R9 fused floor ~91us for the motif pass).

typedef float    f32x4 __attribute__((ext_vector_type(4)));
typedef float    f32x2 __attribute__((ext_vector_type(2)));
typedef unsigned u32x2 __attribute__((ext_vector_type(2)));

__global__ void zero_kernel(float* __restrict__ node_sum, int N,
                            float* __restrict__ out, int G) {
    int i = blockIdx.x * blockDim.x + threadIdx.x;
    if (i < N) node_sum[i] = 0.0f;
    if (i < G) out[i] = 0.0f;
}

// Convert Q,K (f32) -> fp8 e4m3 tables in ws. i indexes groups of 8 floats.
__global__ __launch_bounds__(256) void prep_kernel(
    const f32x4* __restrict__ Q4, const f32x4* __restrict__ K4,
    u32x2* __restrict__ Qf, u32x2* __restrict__ Kf, int n8)
{
    int i = blockIdx.x * blockDim.x + threadIdx.x;
    if (i >= n8) return;
    f32x4 a = __builtin_nontemporal_load(&Q4[2 * i]);
    f32x4 b = __builtin_nontemporal_load(&Q4[2 * i + 1]);
    u32x2 w;
    int lo = __builtin_amdgcn_cvt_pk_fp8_f32(a.x, a.y, 0, false);
    lo     = __builtin_amdgcn_cvt_pk_fp8_f32(a.z, a.w, lo, true);
    int hi = __builtin_amdgcn_cvt_pk_fp8_f32(b.x, b.y, 0, false);
    hi     = __builtin_amdgcn_cvt_pk_fp8_f32(b.z, b.w, hi, true);
    w.x = (unsigned)lo; w.y = (unsigned)hi;
    Qf[i] = w;

    a = __builtin_nontemporal_load(&K4[2 * i]);
    b = __builtin_nontemporal_load(&K4[2 * i + 1]);
    lo = __builtin_amdgcn_cvt_pk_fp8_f32(a.x, a.y, 0, false);
    lo = __builtin_amdgcn_cvt_pk_fp8_f32(a.z, a.w, lo, true);
    hi = __builtin_amdgcn_cvt_pk_fp8_f32(b.x, b.y, 0, false);
    hi = __builtin_amdgcn_cvt_pk_fp8_f32(b.z, b.w, hi, true);
    w.x = (unsigned)lo; w.y = (unsigned)hi;
    Kf[i] = w;
}

// Pass A: gather-only. 8 lanes/motif; lane g reads fp8 words g and g+8 of
// q, ku, kv rows. p = q.(ku*kv), reduced over the 8-lane group -> bellA[m].
__global__ __launch_bounds__(256) void gather_kernel(
    const unsigned* __restrict__ Qf, const unsigned* __restrict__ Kf,
    const int* __restrict__ c3, const int* __restrict__ u3,
    const int* __restrict__ v3, float* __restrict__ bellA, int M)
{
    long long tid = (long long)blockIdx.x * 256 + threadIdx.x;
    int m = (int)(tid >> 3);
    int g = (int)(tid & 7);
    if (m >= M) return;

    int c = c3[m];
    int u = u3[m];
    int v = v3[m];

    unsigned qw0  = Qf[(size_t)c * 16 + g];
    unsigned qw1  = Qf[(size_t)c * 16 + 8 + g];
    unsigned kuw0 = Kf[(size_t)u * 16 + g];
    unsigned kuw1 = Kf[(size_t)u * 16 + 8 + g];
    unsigned kvw0 = Kf[(size_t)v * 16 + g];
    unsigned kvw1 = Kf[(size_t)v * 16 + 8 + g];

    f32x2 q01  = __builtin_amdgcn_cvt_pk_f32_fp8((int)qw0,  false);
    f32x2 q23  = __builtin_amdgcn_cvt_pk_f32_fp8((int)qw0,  true);
    f32x2 q45  = __builtin_amdgcn_cvt_pk_f32_fp8((int)qw1,  false);
    f32x2 q67  = __builtin_amdgcn_cvt_pk_f32_fp8((int)qw1,  true);
    f32x2 ku01 = __builtin_amdgcn_cvt_pk_f32_fp8((int)kuw0, false);
    f32x2 ku23 = __builtin_amdgcn_cvt_pk_f32_fp8((int)kuw0, true);
    f32x2 ku45 = __builtin_amdgcn_cvt_pk_f32_fp8((int)kuw1, false);
    f32x2 ku67 = __builtin_amdgcn_cvt_pk_f32_fp8((int)kuw1, true);
    f32x2 kv01 = __builtin_amdgcn_cvt_pk_f32_fp8((int)kvw0, false);
    f32x2 kv23 = __builtin_amdgcn_cvt_pk_f32_fp8((int)kvw0, true);
    f32x2 kv45 = __builtin_amdgcn_cvt_pk_f32_fp8((int)kvw1, false);
    f32x2 kv67 = __builtin_amdgcn_cvt_pk_f32_fp8((int)kvw1, true);

    float p = q01.x * (ku01.x * kv01.x)
            + q01.y * (ku01.y * kv01.y)
            + q23.x * (ku23.x * kv23.x)
            + q23.y * (ku23.y * kv23.y)
            + q45.x * (ku45.x * kv45.x)
            + q45.y * (ku45.y * kv45.y)
            + q67.x * (ku67.x * kv67.x)
            + q67.y * (ku67.y * kv67.y);

    #pragma unroll
    for (int off = 4; off > 0; off >>= 1)
        p += __shfl_xor(p, off);

    if (g == 0) __builtin_nontemporal_store(p, &bellA[m]);
}

// Pass B: stream T (nt), gather fp8 q only, add bellA, exp + atomic.
__global__ __launch_bounds__(256) void stream_kernel(
    const unsigned* __restrict__ Qf, const f32x4* __restrict__ T4,
    const float* __restrict__ bellA, const float* __restrict__ beta_p,
    const int* __restrict__ c3, float* __restrict__ node_sum,
    int M, float inv_scale)
{
    long long tid = (long long)blockIdx.x * 256 + threadIdx.x;
    int m = (int)(tid >> 3);
    int g = (int)(tid & 7);
    if (m >= M) return;

    int c = c3[m];

    const f32x4* tp = T4 + (size_t)m * 16 + g;
    f32x4 t0 = __builtin_nontemporal_load(tp);      // elems 4g..4g+3
    f32x4 t1 = __builtin_nontemporal_load(tp + 8);  // elems 32+4g..35+4g

    unsigned qw0 = Qf[(size_t)c * 16 + g];
    unsigned qw1 = Qf[(size_t)c * 16 + 8 + g];

    f32x2 q01 = __builtin_amdgcn_cvt_pk_f32_fp8((int)qw0, false);
    f32x2 q23 = __builtin_amdgcn_cvt_pk_f32_fp8((int)qw0, true);
    f32x2 q45 = __builtin_amdgcn_cvt_pk_f32_fp8((int)qw1, false);
    f32x2 q67 = __builtin_amdgcn_cvt_pk_f32_fp8((int)qw1, true);

    float p = q01.x * t0.x + q01.y * t0.y
            + q23.x * t0.z + q23.y * t0.w
            + q45.x * t1.x + q45.y * t1.y
            + q67.x * t1.z + q67.y * t1.w;

    #pragma unroll
    for (int off = 4; off > 0; off >>= 1)
        p += __shfl_xor(p, off);

    if (g == 0) {
        float bell = beta_p[0] * (bellA[m] + p) * inv_scale;
        // |bell| <~ 8.5 -> exp safe in f32, no max-shift pass needed
        atomicAdd(&node_sum[c], __expf(bell));
    }
}

// Per node: lse = log(sum) (or 0 if empty). LDS per-graph reduction (batch is
// sorted -> each 256-node block spans ~1-2 graphs), then scaled atomicAdd.
__global__ __launch_bounds__(256) void node_kernel(
    const float* __restrict__ node_sum, const int* __restrict__ batch,
    const float* __restrict__ lam_p, const float* __restrict__ beta_p,
    float* __restrict__ out, int N, int G)
{
    extern __shared__ float gacc[];
    for (int j = threadIdx.x; j < G; j += blockDim.x) gacc[j] = 0.0f;
    __syncthreads();

    int i = blockIdx.x * blockDim.x + threadIdx.x;
    if (i < N) {
        float s = node_sum[i];
        if (s > 0.0f) {
            atomicAdd(&gacc[batch[i]], logf(s));
        }
    }
    __syncthreads();

    float coef = lam_p[0] / beta_p[0];
    for (int j = threadIdx.x; j < G; j += blockDim.x) {
        float v = gacc[j];
        if (v != 0.0f) atomicAdd(&out[j], coef * v);
    }
}

extern "C" void kernel_launch(void* const* d_in, const int* in_sizes, int n_in,
                              void* d_out, int out_size, void* d_ws, size_t ws_size,
                              hipStream_t stream) {
    const float* Q    = (const float*)d_in[0];
    const float* K    = (const float*)d_in[1];
    const float* T    = (const float*)d_in[2];
    const float* lam  = (const float*)d_in[3];
    const float* beta = (const float*)d_in[4];
    const int* c3     = (const int*)d_in[5];
    const int* u3     = (const int*)d_in[6];
    const int* v3     = (const int*)d_in[7];
    const int* batch  = (const int*)d_in[8];

    const int M = in_sizes[5];          // 1,000,000
    const int N = in_sizes[8];          // 100,000
    const int G = out_size;             // 128
    const int RD = in_sizes[0] / N;     // R*D = 64
    const int n8 = in_sizes[0] / 8;     // 8-float groups per table
    const float inv_scale = 1.0f / sqrtf((float)RD);

    // ws: node_sum (N f32) | bellA (M f32) | Qf (fp8) | Kf (fp8)
    float* node_sum = (float*)d_ws;
    size_t off = (((size_t)N * sizeof(float)) + 1023) & ~(size_t)1023;
    float* bellA = (float*)((char*)d_ws + off);
    off += (((size_t)M * sizeof(float)) + 1023) & ~(size_t)1023;
    unsigned* Qf = (unsigned*)((char*)d_ws + off);
    unsigned* Kf = Qf + (size_t)n8 * 2;
    float* out = (float*)d_out;

    int zmax = (N > G) ? N : G;
    zero_kernel<<<(zmax + 255) / 256, 256, 0, stream>>>(node_sum, N, out, G);

    prep_kernel<<<(n8 + 255) / 256, 256, 0, stream>>>(
        (const f32x4*)Q, (const f32x4*)K, (u32x2*)Qf, (u32x2*)Kf, n8);

    long long total_threads = (long long)M * 8;
    int mgrid = (int)((total_threads + 255) / 256);

    gather_kernel<<<mgrid, 256, 0, stream>>>(
        Qf, Kf, c3, u3, v3, bellA, M);

    stream_kernel<<<mgrid, 256, 0, stream>>>(
        Qf, (const f32x4*)T, bellA, beta, c3, node_sum, M, inv_scale);

    node_kernel<<<(N + 255) / 256, 256, G * sizeof(float), stream>>>(
        node_sum, batch, lam, beta, out, N, G);
}

// Round 11
// 109.966 us; speedup vs baseline: 1.1732x; 1.1732x over previous
//
#include <hip/hip_runtime.h>
#include <math.h>

// N_NODES=100000, N_MOTIFS=1000000, R_DIM=1, D_DIM=64, N_GRAPHS=128.
// fp8 row = 64 B = 16 u32 words, stored PERMUTED: pos 2g = natural word g,
// pos 2g+1 = natural word g+8. Lane g then reads ONE dwordx2 per row and
// gets elements {4g..4g+3, 32+4g..35+4g}, matching T's split-chunk loads
// (chunks g and g+8, each instruction a full 128-B line).
//
// Model (R1-R10): bound by mixed stream+random-gather service (~5 TB/s on
// ~460 MB). Byte cuts worked (f32->fp16->fp8: 153->136->108); structural
// probes (split, persistent, cache hints) all null/negative. R11: halve
// gather request count (6x4B -> 3x8B) + 2-motif unroll for MLP.

typedef float    f32x4 __attribute__((ext_vector_type(4)));
typedef float    f32x2 __attribute__((ext_vector_type(2)));
typedef unsigned u32x2 __attribute__((ext_vector_type(2)));

__global__ void zero_kernel(float* __restrict__ node_sum, int N,
                            float* __restrict__ out, int G) {
    int i = blockIdx.x * blockDim.x + threadIdx.x;
    if (i < N) node_sum[i] = 0.0f;
    if (i < G) out[i] = 0.0f;
}

// Convert Q,K (f32) -> fp8 e4m3 tables, permuted layout. Thread t: row
// r = t>>3, slot g = t&7. Reads row chunks g and g+8 (f32x4 each, both
// instructions 128-B coalesced across the 8 slots), packs to one u32x2 at
// row offset 2g (8-B coalesced store).
__global__ __launch_bounds__(256) void prep_kernel(
    const f32x4* __restrict__ Q4, const f32x4* __restrict__ K4,
    u32x2* __restrict__ Qf, u32x2* __restrict__ Kf, int nt)
{
    int t = blockIdx.x * blockDim.x + threadIdx.x;
    if (t >= nt) return;
    int r = t >> 3;
    int g = t & 7;
    size_t base = (size_t)r * 16 + g;

    f32x4 a = __builtin_nontemporal_load(&Q4[base]);      // chunk g
    f32x4 b = __builtin_nontemporal_load(&Q4[base + 8]);  // chunk g+8
    u32x2 w;
    int lo = __builtin_amdgcn_cvt_pk_fp8_f32(a.x, a.y, 0, false);
    lo     = __builtin_amdgcn_cvt_pk_fp8_f32(a.z, a.w, lo, true);
    int hi = __builtin_amdgcn_cvt_pk_fp8_f32(b.x, b.y, 0, false);
    hi     = __builtin_amdgcn_cvt_pk_fp8_f32(b.z, b.w, hi, true);
    w.x = (unsigned)lo; w.y = (unsigned)hi;
    Qf[(size_t)r * 8 + g] = w;

    a = __builtin_nontemporal_load(&K4[base]);
    b = __builtin_nontemporal_load(&K4[base + 8]);
    lo = __builtin_amdgcn_cvt_pk_fp8_f32(a.x, a.y, 0, false);
    lo = __builtin_amdgcn_cvt_pk_fp8_f32(a.z, a.w, lo, true);
    hi = __builtin_amdgcn_cvt_pk_fp8_f32(b.x, b.y, 0, false);
    hi = __builtin_amdgcn_cvt_pk_fp8_f32(b.z, b.w, hi, true);
    w.x = (unsigned)lo; w.y = (unsigned)hi;
    Kf[(size_t)r * 8 + g] = w;
}

__device__ __forceinline__ float motif_dot(
    u32x2 qw, u32x2 kuw, u32x2 kvw, f32x4 t0, f32x4 t1)
{
    f32x2 q01  = __builtin_amdgcn_cvt_pk_f32_fp8((int)qw.x,  false);
    f32x2 q23  = __builtin_amdgcn_cvt_pk_f32_fp8((int)qw.x,  true);
    f32x2 q45  = __builtin_amdgcn_cvt_pk_f32_fp8((int)qw.y,  false);
    f32x2 q67  = __builtin_amdgcn_cvt_pk_f32_fp8((int)qw.y,  true);
    f32x2 ku01 = __builtin_amdgcn_cvt_pk_f32_fp8((int)kuw.x, false);
    f32x2 ku23 = __builtin_amdgcn_cvt_pk_f32_fp8((int)kuw.x, true);
    f32x2 ku45 = __builtin_amdgcn_cvt_pk_f32_fp8((int)kuw.y, false);
    f32x2 ku67 = __builtin_amdgcn_cvt_pk_f32_fp8((int)kuw.y, true);
    f32x2 kv01 = __builtin_amdgcn_cvt_pk_f32_fp8((int)kvw.x, false);
    f32x2 kv23 = __builtin_amdgcn_cvt_pk_f32_fp8((int)kvw.x, true);
    f32x2 kv45 = __builtin_amdgcn_cvt_pk_f32_fp8((int)kvw.y, false);
    f32x2 kv67 = __builtin_amdgcn_cvt_pk_f32_fp8((int)kvw.y, true);

    return q01.x * fmaf(ku01.x, kv01.x, t0.x)
         + q01.y * fmaf(ku01.y, kv01.y, t0.y)
         + q23.x * fmaf(ku23.x, kv23.x, t0.z)
         + q23.y * fmaf(ku23.y, kv23.y, t0.w)
         + q45.x * fmaf(ku45.x, kv45.x, t1.x)
         + q45.y * fmaf(ku45.y, kv45.y, t1.y)
         + q67.x * fmaf(ku67.x, kv67.x, t1.z)
         + q67.y * fmaf(ku67.y, kv67.y, t1.w);
}

// Fused motif pass: 8 lanes per motif, 2 motifs per thread (unrolled for
// MLP). Lane g, motif m: T chunks g and g+8 (each load = one full 128-B
// line across the group, nt); one u32x2 gather per table row.
__global__ __launch_bounds__(256) void motif_kernel(
    const u32x2* __restrict__ Qf, const u32x2* __restrict__ Kf,
    const f32x4* __restrict__ T4, const float* __restrict__ beta_p,
    const int* __restrict__ c3, const int* __restrict__ u3,
    const int* __restrict__ v3, float* __restrict__ node_sum,
    int M, float inv_scale)
{
    long long tid = (long long)blockIdx.x * 256 + threadIdx.x;
    int pi = (int)(tid >> 3);      // pair index
    int g  = (int)(tid & 7);
    int m0 = 2 * pi;
    if (m0 >= M) return;
    int m1 = m0 + 1;
    bool has1 = (m1 < M);

    int c0 = c3[m0], u0 = u3[m0], v0 = v3[m0];
    int c1 = c0, u1 = u0, v1 = v0;
    if (has1) { c1 = c3[m1]; u1 = u3[m1]; v1 = v3[m1]; }

    // issue all loads for both motifs up front
    const f32x4* tp0 = T4 + (size_t)m0 * 16 + g;
    f32x4 t00 = __builtin_nontemporal_load(tp0);
    f32x4 t01 = __builtin_nontemporal_load(tp0 + 8);
    u32x2 qw0  = Qf[(size_t)c0 * 8 + g];
    u32x2 kuw0 = Kf[(size_t)u0 * 8 + g];
    u32x2 kvw0 = Kf[(size_t)v0 * 8 + g];

    f32x4 t10 = t00, t11 = t01;
    u32x2 qw1 = qw0, kuw1 = kuw0, kvw1 = kvw0;
    if (has1) {
        const f32x4* tp1 = T4 + (size_t)m1 * 16 + g;
        t10 = __builtin_nontemporal_load(tp1);
        t11 = __builtin_nontemporal_load(tp1 + 8);
        qw1  = Qf[(size_t)c1 * 8 + g];
        kuw1 = Kf[(size_t)u1 * 8 + g];
        kvw1 = Kf[(size_t)v1 * 8 + g];
    }

    float p0 = motif_dot(qw0, kuw0, kvw0, t00, t01);
    float p1 = motif_dot(qw1, kuw1, kvw1, t10, t11);

    // reduce both across the 8-lane group (xor masks < 8 stay in-group)
    #pragma unroll
    for (int off = 4; off > 0; off >>= 1) {
        p0 += __shfl_xor(p0, off);
        p1 += __shfl_xor(p1, off);
    }

    if (g == 0) {
        float bs = beta_p[0] * inv_scale;
        // |bell| <~ 8.5 -> exp safe in f32, no max-shift pass needed
        atomicAdd(&node_sum[c0], __expf(bs * p0));
        if (has1) atomicAdd(&node_sum[c1], __expf(bs * p1));
    }
}

// Per node: lse = log(sum) (or 0 if empty). LDS per-graph reduction (batch is
// sorted -> each 256-node block spans ~1-2 graphs), then scaled atomicAdd.
__global__ __launch_bounds__(256) void node_kernel(
    const float* __restrict__ node_sum, const int* __restrict__ batch,
    const float* __restrict__ lam_p, const float* __restrict__ beta_p,
    float* __restrict__ out, int N, int G)
{
    extern __shared__ float gacc[];
    for (int j = threadIdx.x; j < G; j += blockDim.x) gacc[j] = 0.0f;
    __syncthreads();

    int i = blockIdx.x * blockDim.x + threadIdx.x;
    if (i < N) {
        float s = node_sum[i];
        if (s > 0.0f) {
            atomicAdd(&gacc[batch[i]], logf(s));
        }
    }
    __syncthreads();

    float coef = lam_p[0] / beta_p[0];
    for (int j = threadIdx.x; j < G; j += blockDim.x) {
        float v = gacc[j];
        if (v != 0.0f) atomicAdd(&out[j], coef * v);
    }
}

extern "C" void kernel_launch(void* const* d_in, const int* in_sizes, int n_in,
                              void* d_out, int out_size, void* d_ws, size_t ws_size,
                              hipStream_t stream) {
    const float* Q    = (const float*)d_in[0];
    const float* K    = (const float*)d_in[1];
    const float* T    = (const float*)d_in[2];
    const float* lam  = (const float*)d_in[3];
    const float* beta = (const float*)d_in[4];
    const int* c3     = (const int*)d_in[5];
    const int* u3     = (const int*)d_in[6];
    const int* v3     = (const int*)d_in[7];
    const int* batch  = (const int*)d_in[8];

    const int M = in_sizes[5];          // 1,000,000
    const int N = in_sizes[8];          // 100,000
    const int G = out_size;             // 128
    const int RD = in_sizes[0] / N;     // R*D = 64
    const int nt = in_sizes[0] / 8;     // 8-float groups per table
    const float inv_scale = 1.0f / sqrtf((float)RD);

    // ws layout: node_sum (N f32) | Qf (N*RD fp8) | Kf (N*RD fp8)
    float* node_sum = (float*)d_ws;
    size_t off = (((size_t)N * sizeof(float)) + 1023) & ~(size_t)1023;
    u32x2* Qf = (u32x2*)((char*)d_ws + off);
    u32x2* Kf = Qf + nt;
    float* out = (float*)d_out;

    int zmax = (N > G) ? N : G;
    zero_kernel<<<(zmax + 255) / 256, 256, 0, stream>>>(node_sum, N, out, G);

    prep_kernel<<<(nt + 255) / 256, 256, 0, stream>>>(
        (const f32x4*)Q, (const f32x4*)K, Qf, Kf, nt);

    // 8 threads per motif pair
    long long pairs = (M + 1) / 2;
    long long total_threads = pairs * 8;
    int mgrid = (int)((total_threads + 255) / 256);
    motif_kernel<<<mgrid, 256, 0, stream>>>(
        Qf, Kf, (const f32x4*)T, beta, c3, u3, v3, node_sum, M, inv_scale);

    node_kernel<<<(N + 255) / 256, 256, G * sizeof(float), stream>>>(
        node_sum, batch, lam, beta, out, N, G);
}